// Round 14
// baseline (393.818 us; speedup 1.0000x reference)
//
#include <hip/hip_runtime.h>
#include <hip/hip_bf16.h>
#include <math.h>

typedef __bf16 bhalf;
typedef __bf16 bhalf8 __attribute__((ext_vector_type(8)));
typedef float  floatx4 __attribute__((ext_vector_type(4)));
typedef float  floatx8 __attribute__((ext_vector_type(8)));
typedef unsigned short ushort_t;
typedef unsigned short ushort8 __attribute__((ext_vector_type(8)));

#define MFMA16(a, b, c) __builtin_amdgcn_mfma_f32_16x16x32_bf16((a), (b), (c), 0, 0, 0)

__device__ __forceinline__ void gload_lds16(const bhalf* g, bhalf* l)
{
    __builtin_amdgcn_global_load_lds((const __attribute__((address_space(1))) void*)g,
                                     (__attribute__((address_space(3))) void*)l, 16, 0, 0);
}

enum { EPI_PLAIN = 0, EPI_RES = 1, EPI_GELU = 2, EPI_QKV = 3 };

// ---------------------------------------------------------------------------
// Per-block dtype self-detection (replaces the detect_dtype launch + flag).
// Reads the first 2048 ushorts of x (same 4 KB for every block -> L2-hot).
// bf16 data: exponent field (bits 14:7) < 0x90 for |v| < 2^17 -> ~0 hits.
// f32 data: even-index ushorts are mantissa-low bits, ~uniform -> ~448/1024
// hits. Threshold 32 has huge margin both ways. Must be called uniformly
// by all threads of the block (contains barriers).
// ---------------------------------------------------------------------------
__device__ __forceinline__ bool detect_f32_block(const ushort_t* __restrict__ x)
{
    __shared__ int tot_det;
    const int tid = threadIdx.x;
    if (tid == 0) tot_det = 0;
    __syncthreads();
    const ushort8 u = *(const ushort8*)(x + (size_t)tid * 8);
    int cnt = 0;
#pragma unroll
    for (int j = 0; j < 8; j += 2) {
        const int e = (u[j] >> 7) & 0xFF;
        if (e >= 0x90) ++cnt;
    }
    atomicAdd(&tot_det, cnt);
    __syncthreads();
    return tot_det > 32;
}

// ---------------------------------------------------------------------------
// FUSED preprocess: norm_x (blocks 0..2047) + norm_vec (2048..2067) +
// transpose_all (2068..14355) in ONE launch; each block self-detects dtype.
// All three sub-tasks are independent (read inputs, write distinct ws).
// ---------------------------------------------------------------------------
struct Cvt { const void* s; bhalf* d; int n; };
struct CvtArr { Cvt t[10]; };
struct TDesc { const void* src; bhalf* dst; int R, C; };
struct TDescArr { TDesc t[6]; };

__global__ __launch_bounds__(256) void preprocess(
    const void* __restrict__ x, bhalf* __restrict__ x_n, CvtArr cv, TDescArr a)
{
    __shared__ bhalf sm[32][33];
    const bool f32 = detect_f32_block((const ushort_t*)x);
    const int bid = blockIdx.x;
    const int tid = threadIdx.x;

    if (bid < 2048) {
        // ---- norm_x ----
        const int i = (bid * 256 + tid) * 8;
        if (f32) {
            const floatx8 v = *(const floatx8*)((const float*)x + i);
            bhalf8 o;
#pragma unroll
            for (int j = 0; j < 8; ++j) o[j] = (bhalf)v[j];
            *(bhalf8*)(x_n + i) = o;
        } else {
            *(ushort8*)((ushort_t*)x_n + i) = *(const ushort8*)((const ushort_t*)x + i);
        }
        return;
    }
    if (bid < 2068) {
        // ---- norm_vec ----
        const int vid = bid - 2048;
        const Cvt c = cv.t[vid >> 1];
        const int i = ((vid & 1) * 256 + tid) * 8;
        if (i >= c.n) return;
        if (f32) {
            const floatx8 v = *(const floatx8*)((const float*)c.s + i);
            bhalf8 o;
#pragma unroll
            for (int j = 0; j < 8; ++j) o[j] = (bhalf)v[j];
            *(bhalf8*)(c.d + i) = o;
        } else {
            *(ushort8*)((ushort_t*)c.d + i) = *(const ushort8*)((const ushort_t*)c.s + i);
        }
        return;
    }
    // ---- transpose_all ----
    const int id = bid - 2068;
    TDesc d;
    int rem;
    if (id < 4096)      { d = a.t[id >> 10]; rem = id & 1023; }
    else if (id < 8192) { d = a.t[4];        rem = id - 4096; }
    else                { d = a.t[5];        rem = id - 8192; }
    const int txc = d.C >> 5;
    const int bx = (rem % txc) * 32;
    const int by = (rem / txc) * 32;
    const int tx = tid & 31;
    const int ty = tid >> 5;
    if (f32) {
        const float* fin = (const float*)d.src;
#pragma unroll
        for (int i = 0; i < 4; ++i)
            sm[ty + i * 8][tx] = (bhalf)fin[(size_t)(by + ty + i * 8) * d.C + bx + tx];
    } else {
        const bhalf* bin = (const bhalf*)d.src;
#pragma unroll
        for (int i = 0; i < 4; ++i)
            sm[ty + i * 8][tx] = bin[(size_t)(by + ty + i * 8) * d.C + bx + tx];
    }
    __syncthreads();
#pragma unroll
    for (int i = 0; i < 4; ++i)
        d.dst[(size_t)(bx + ty + i * 8) * d.R + by + tx] = sm[tx][ty + i * 8];
}

// ---------------------------------------------------------------------------
// V transpose: Vw[b*2048+t][h*64+dk] -> Vt[(b*16+h)*64+dk][t]. Coalesced.
// ---------------------------------------------------------------------------
__global__ __launch_bounds__(256) void vt_transpose(const bhalf* __restrict__ Vw,
                                                    bhalf* __restrict__ Vt)
{
    __shared__ bhalf sm[32][33];
    const int bh = blockIdx.z;
    const int b = bh >> 4, h = bh & 15;
    const int tb = blockIdx.y * 32;
    const int db = blockIdx.x * 32;
    const int tx = threadIdx.x & 31;
    const int ty = threadIdx.x >> 5;
#pragma unroll
    for (int i = 0; i < 4; ++i)
        sm[ty + i * 8][tx] = Vw[(size_t)(b * 2048 + tb + ty + i * 8) * 1024 + h * 64 + db + tx];
    __syncthreads();
#pragma unroll
    for (int i = 0; i < 4; ++i)
        Vt[(size_t)(bh * 64 + db + ty + i * 8) * 2048 + tb + tx] = sm[tx][ty + i * 8];
}

// ---------------------------------------------------------------------------
// UNIFIED GEMM: 128x64 tile, BK=64, 256 threads (4 waves, wave owns 32x64),
// TRIPLE-buffered LDS (72 KB dynamic -> 2 blocks/CU), prefetch 2 K-tiles
// ahead, counted vmcnt, one barrier per body (round-12/13 verified: 0 bank
// conflicts, FETCH within 5% of ideal after hierarchical mapping).
// Hierarchical tile-id mapping (round 13): XCD chunk traversed in COLUMN
// GROUPS of 16 -> concurrent L2 working set ~3 MB < 4 MB XCD L2.
// Body t: { ds_read 12 frags buf(t%3); stage(t+2)->buf((t+2)%3);
//           16 MFMA (setprio); vmcnt(6) confirms tile t+1; barrier }
// ---------------------------------------------------------------------------
template <int EPI>
__global__ __launch_bounds__(256) void gemm_3b(
    const bhalf* __restrict__ A, int lda,
    const bhalf* __restrict__ BT, int ldb,
    const bhalf* __restrict__ bias,
    const bhalf* __restrict__ resid,
    bhalf* __restrict__ C, int ldc, int K, int nbx,
    bhalf* __restrict__ Ck, bhalf* __restrict__ Cv)
{
    extern __shared__ __align__(16) bhalf sm[];   // A: 3x8192 | B(at 24576): 3x4096

    const int tid  = threadIdx.x;
    const int lane = tid & 63;
    const int w    = tid >> 6;
    const int l15  = lane & 15;
    const int q    = lane >> 4;
    const int wm   = w * 32;

    // XCD chunk + column-grouped traversal (W=16), bijective
    const int nwg = gridDim.x;
    const int cpx = nwg >> 3;
    const int xcd = blockIdx.x & 7;
    const int idc = blockIdx.x >> 3;
    const int rc  = cpx / nbx;
    const int gsz = rc * 16;
    const int g   = idc / gsz;
    const int rm  = idc % gsz;
    const int row = xcd * rc + rm / 16;
    const int col = g * 16 + (rm & 15);
    const int n0  = col * 64;
    const int m0  = row * 128;

    const int r8 = lane >> 3;
    const int c8 = lane & 7;
    const int gc = (c8 ^ r8) << 3;

    floatx4 acc[2][4];
#pragma unroll
    for (int i = 0; i < 2; ++i)
#pragma unroll
        for (int j = 0; j < 4; ++j) acc[i][j] = (floatx4){0.f, 0.f, 0.f, 0.f};

    const bhalf* Ab = A  + (size_t)(m0 + r8) * lda + gc;
    const bhalf* Bb = BT + (size_t)(n0 + r8) * ldb + gc;

    auto stage = [&](int buf, int k0) {
        bhalf* as = sm + buf * 8192;
        bhalf* bs = sm + 24576 + buf * 4096;
#pragma unroll
        for (int i = 0; i < 4; ++i) {
            const int rb = w * 32 + i * 8;
            gload_lds16(Ab + (size_t)rb * lda + k0, as + rb * 64 + lane * 8);
        }
#pragma unroll
        for (int i = 0; i < 2; ++i) {
            const int rb = w * 16 + i * 8;
            gload_lds16(Bb + (size_t)rb * ldb + k0, bs + rb * 64 + lane * 8);
        }
    };

    // prologue: tiles 0,1 issued (12 loads); confirm tile 0 (6 newest in flight)
    stage(0, 0);
    stage(1, 64);
    asm volatile("s_waitcnt vmcnt(6)" ::: "memory");
    __builtin_amdgcn_s_barrier();
    asm volatile("" ::: "memory");

    const int NT = K >> 6;
    for (int t = 0; t < NT; ++t) {
        const int buf = t % 3;
        const bhalf* as = sm + buf * 8192;
        const bhalf* bs = sm + 24576 + buf * 4096;

        bhalf8 af[2][2], bf[2][4];
#pragma unroll
        for (int ks = 0; ks < 2; ++ks) {
            const int pc = (((ks * 4 + q) ^ (l15 & 7)) << 3);
#pragma unroll
            for (int mt = 0; mt < 2; ++mt)
                af[ks][mt] = *(const bhalf8*)&as[(wm + mt * 16 + l15) * 64 + pc];
#pragma unroll
            for (int nt = 0; nt < 4; ++nt)
                bf[ks][nt] = *(const bhalf8*)&bs[(nt * 16 + l15) * 64 + pc];
        }

        if (t + 2 < NT) stage((t + 2) % 3, (t + 2) << 6);

        __builtin_amdgcn_s_setprio(1);
#pragma unroll
        for (int ks = 0; ks < 2; ++ks)
#pragma unroll
            for (int mt = 0; mt < 2; ++mt)
#pragma unroll
                for (int nt = 0; nt < 4; ++nt)
                    acc[mt][nt] = MFMA16(af[ks][mt], bf[ks][nt], acc[mt][nt]);
        __builtin_amdgcn_s_setprio(0);

        if (t + 2 < NT) {
            asm volatile("s_waitcnt vmcnt(6)" ::: "memory");
        } else if (t + 1 < NT) {
            asm volatile("s_waitcnt vmcnt(0)" ::: "memory");
        }
        if (t + 1 < NT) {
            __builtin_amdgcn_s_barrier();
            asm volatile("" ::: "memory");
        }
    }

#pragma unroll
    for (int mt = 0; mt < 2; ++mt)
#pragma unroll
        for (int nt = 0; nt < 4; ++nt) {
            const int col2 = n0 + nt * 16 + l15;
            const float bv = (float)bias[col2];
#pragma unroll
            for (int r = 0; r < 4; ++r) {
                const int row2 = m0 + wm + mt * 16 + q * 4 + r;
                float v = acc[mt][nt][r] + bv;
                if constexpr (EPI == EPI_RES) {
                    v += (float)resid[(size_t)row2 * ldc + col2];
                    C[(size_t)row2 * ldc + col2] = (bhalf)v;
                } else if constexpr (EPI == EPI_GELU) {
                    v = 0.5f * v * (1.f + erff(v * 0.70710678118654752f));
                    C[(size_t)row2 * ldc + col2] = (bhalf)v;
                } else if constexpr (EPI == EPI_QKV) {
                    if (col2 < 1024)       C [(size_t)row2 * 1024 + col2]        = (bhalf)v;
                    else if (col2 < 2048)  Ck[(size_t)row2 * 1024 + col2 - 1024] = (bhalf)v;
                    else                   Cv[(size_t)row2 * 1024 + col2 - 2048] = (bhalf)v;
                } else {
                    C[(size_t)row2 * ldc + col2] = (bhalf)v;
                }
            }
        }
}

// ---------------------------------------------------------------------------
// Flash attention v3: P never touches LDS (swapped QK^T, permuted K rows,
// in-register P pack). Constant-max softmax in exp2 domain. XCD swizzle.
// LDS = 32 KB. (Unchanged.)
// ---------------------------------------------------------------------------
__global__ __launch_bounds__(256) void flash_attn(
    const bhalf* __restrict__ Q, const bhalf* __restrict__ Km,
    const bhalf* __restrict__ Vt, bhalf* __restrict__ ctx)
{
    __shared__ __align__(16) bhalf Ks[2][64 * 64];
    __shared__ __align__(16) bhalf Vs[2][64 * 64];

    const int tid  = threadIdx.x;
    const int lane = tid & 63;
    const int wq   = tid >> 6;
    const int l15  = lane & 15;
    const int q    = lane >> 4;
    const int bh   = blockIdx.x & 31;   // XCD-affine: same head -> same XCD
    const int l0   = (blockIdx.x >> 5) * 64;
    const int b    = bh >> 4, h = bh & 15;
    const float SC = 0.125f * 1.44269504f;

    const bhalf* qp = Q + ((size_t)(b * 2048 + l0 + wq * 16 + l15)) * 1024 + h * 64 + q * 8;
    const bhalf8 aQ0 = *(const bhalf8*)qp;
    const bhalf8 aQ1 = *(const bhalf8*)(qp + 32);

    float ps = 0.f;
    floatx4 o[4];
#pragma unroll
    for (int ot = 0; ot < 4; ++ot) o[ot] = (floatx4){0.f, 0.f, 0.f, 0.f};

    const int r8 = lane >> 3;
    const int c8 = lane & 7;
    const bhalf* kbase = Km + ((size_t)(b * 2048)) * 1024 + h * 64;
    const bhalf* vbase = Vt + ((size_t)(bh * 64)) * 2048;

    auto stage = [&](int buf, int kt) {
#pragma unroll
        for (int i = 0; i < 2; ++i) {
            const int rb = wq * 16 + i * 8;
            const int fk = (((rb >> 3) << 1) ^ r8) & 7;   // K swizzle f(row)
            gload_lds16(kbase + (size_t)(kt + rb + r8) * 1024 + ((c8 ^ fk) << 3),
                        &Ks[buf][rb * 64] + lane * 8);
            gload_lds16(vbase + (size_t)(rb + r8) * 2048 + kt + ((c8 ^ r8) << 3),
                        &Vs[buf][rb * 64] + lane * 8);
        }
    };

    stage(0, 0);
    int cur = 0;
    for (int kt = 0; kt < 2048; kt += 64) {
        __syncthreads();
        if (kt + 64 < 2048) stage(cur ^ 1, kt + 64);

        // ---- S^T = K Q^T (swapped, permuted K rows) ----
        floatx4 s[4];
#pragma unroll
        for (int nt = 0; nt < 4; ++nt) {
            const int row = (nt >> 1) * 32 + (nt & 1) * 4 + ((l15 >> 2) << 3) + (l15 & 3);
            const int f = (((row >> 3) << 1) ^ row) & 7;
            const bhalf8 k0 = *(const bhalf8*)&Ks[cur][row * 64 + ((q ^ f) << 3)];
            const bhalf8 k1 = *(const bhalf8*)&Ks[cur][row * 64 + (((4 + q) ^ f) << 3)];
            floatx4 z = (floatx4){0.f, 0.f, 0.f, 0.f};
            z = MFMA16(k0, aQ0, z);
            s[nt] = MFMA16(k1, aQ1, z);
        }

        // ---- softmax + pack P into PV A-frags (all in registers) ----
        bhalf8 pa[2];
#pragma unroll
        for (int nt = 0; nt < 4; ++nt)
#pragma unroll
            for (int r = 0; r < 4; ++r) {
                const float pv = __builtin_amdgcn_exp2f(fmaf(s[nt][r], SC, -8.f));
                ps += pv;
                pa[nt >> 1][(nt & 1) * 4 + r] = (bhalf)pv;
            }

        // ---- O += P V ----
#pragma unroll
        for (int kc = 0; kc < 2; ++kc)
#pragma unroll
            for (int ot = 0; ot < 4; ++ot) {
                const bhalf8 bV = *(const bhalf8*)&Vs[cur][(ot * 16 + l15) * 64 + (((kc * 4 + q) ^ (l15 & 7)) << 3)];
                o[ot] = MFMA16(pa[kc], bV, o[ot]);
            }
        cur ^= 1;
    }

    // epilogue: denom(query l15) -> redistribute to o rows (query q*4+r)
    ps += __shfl_xor(ps, 16);
    ps += __shfl_xor(ps, 32);
    const float invq = 1.f / ps;
    float inv[4];
#pragma unroll
    for (int r = 0; r < 4; ++r)
        inv[r] = __shfl(invq, (lane & 48) | (q * 4 + r));

#pragma unroll
    for (int ot = 0; ot < 4; ++ot)
#pragma unroll
        for (int r = 0; r < 4; ++r) {
            const int l = l0 + wq * 16 + q * 4 + r;
            const int kk = ot * 16 + l15;
            const int R = h * 128 + (l >> 4);
            const int Cc = (l & 15) * 64 + kk;
            ctx[((size_t)(b * 2048 + R)) * 1024 + Cc] = (bhalf)(o[ot][r] * inv[r]);
        }
}

// ---------------------------------------------------------------------------
// Row LayerNorm, 2 rows/block, bhalf8 vector loads, fp32 stats.
// xdet == nullptr -> bf16 output; else self-detect dtype from xdet.
// ---------------------------------------------------------------------------
__global__ __launch_bounds__(256) void ln_kernel(
    const bhalf* __restrict__ X, const bhalf* __restrict__ g,
    const bhalf* __restrict__ be, void* __restrict__ out,
    const ushort_t* __restrict__ xdet)
{
    __shared__ float red[4][2];
    const bool f32 = xdet && detect_f32_block(xdet);
    const int tid = threadIdx.x;
    const int wid = tid >> 6;
    const int rid = tid >> 7;
    const int lt  = tid & 127;
    const int row = blockIdx.x * 2 + rid;
    const int col = lt * 8;
    const bhalf8 xv = *(const bhalf8*)(X + (size_t)row * 1024 + col);
    float v[8], s1 = 0.f, s2 = 0.f;
#pragma unroll
    for (int i = 0; i < 8; ++i) {
        v[i] = (float)xv[i];
        s1 += v[i];
        s2 += v[i] * v[i];
    }
#pragma unroll
    for (int off = 1; off < 64; off <<= 1) {
        s1 += __shfl_xor(s1, off);
        s2 += __shfl_xor(s2, off);
    }
    if ((tid & 63) == 0) { red[wid][0] = s1; red[wid][1] = s2; }
    __syncthreads();
    const float t1 = red[rid * 2][0] + red[rid * 2 + 1][0];
    const float t2 = red[rid * 2][1] + red[rid * 2 + 1][1];
    const float mu = t1 * (1.f / 1024.f);
    const float rs = rsqrtf(t2 * (1.f / 1024.f) - mu * mu + 1e-5f);
    if (f32) {
        floatx8 ov;
#pragma unroll
        for (int i = 0; i < 8; ++i)
            ov[i] = ((v[i] - mu) * rs) * (float)g[col + i] + (float)be[col + i];
        *(floatx8*)((float*)out + (size_t)row * 1024 + col) = ov;
    } else {
        bhalf8 ov;
#pragma unroll
        for (int i = 0; i < 8; ++i)
            ov[i] = (bhalf)(((v[i] - mu) * rs) * (float)g[col + i] + (float)be[col + i]);
        *(bhalf8*)((bhalf*)out + (size_t)row * 1024 + col) = ov;
    }
}

// ---------------------------------------------------------------------------
extern "C" void kernel_launch(void* const* d_in, const int* in_sizes, int n_in,
                              void* d_out, int out_size, void* d_ws, size_t ws_size,
                              hipStream_t stream)
{
    (void)in_sizes; (void)n_in; (void)out_size; (void)ws_size;

    char* p = (char*)d_ws;
    const size_t MB = 1024 * 1024;
    bhalf* vecs  = (bhalf*)(p + 128 * 1024);
    bhalf* Qw    = (bhalf*)(p + 1 * MB);
    bhalf* Kw    = (bhalf*)(p + 9 * MB);
    bhalf* Vw    = (bhalf*)(p + 17 * MB);
    bhalf* Vt    = (bhalf*)(p + 25 * MB);
    bhalf* x_n   = (bhalf*)(p + 33 * MB);
    bhalf* WqkvT = (bhalf*)(p + 41 * MB);
    bhalf* WoT   = (bhalf*)(p + 47 * MB);
    bhalf* W1T   = (bhalf*)(p + 49 * MB);
    bhalf* W2T   = (bhalf*)(p + 57 * MB);
    bhalf* ctx   = Vw;                    // after vt_transpose
    bhalf* ff1   = (bhalf*)(p + 17 * MB); // 32 MB, prior occupants dead
    bhalf* ln1   = Qw;
    bhalf* x1    = Kw;
    bhalf* ff2   = Qw;

    bhalf* bqkv  = vecs;
    bhalf* bo_n  = vecs + 1 * 4096;
    bhalf* b1_n  = vecs + 2 * 4096;
    bhalf* b2_n  = vecs + 3 * 4096;
    bhalf* g1_n  = vecs + 4 * 4096;
    bhalf* be1_n = vecs + 5 * 4096;
    bhalf* g2_n  = vecs + 6 * 4096;
    bhalf* be2_n = vecs + 7 * 4096;

    static bool attr_done = false;
    if (!attr_done) {
        hipFuncSetAttribute((const void*)gemm_3b<EPI_QKV>,
                            hipFuncAttributeMaxDynamicSharedMemorySize, 73728);
        hipFuncSetAttribute((const void*)gemm_3b<EPI_RES>,
                            hipFuncAttributeMaxDynamicSharedMemorySize, 73728);
        hipFuncSetAttribute((const void*)gemm_3b<EPI_GELU>,
                            hipFuncAttributeMaxDynamicSharedMemorySize, 73728);
        attr_done = true;
    }

    const dim3 blk(256);

    // ONE fused preprocess launch: norm_x + 10 vec converts + 6 transposes
    CvtArr arr;
    arr.t[0] = {d_in[2],  bqkv,        1024};
    arr.t[1] = {d_in[4],  bqkv + 1024, 1024};
    arr.t[2] = {d_in[6],  bqkv + 2048, 1024};
    arr.t[3] = {d_in[8],  bo_n,        1024};
    arr.t[4] = {d_in[10], b1_n,        4096};
    arr.t[5] = {d_in[12], b2_n,        1024};
    arr.t[6] = {d_in[13], g1_n,        1024};
    arr.t[7] = {d_in[14], be1_n,       1024};
    arr.t[8] = {d_in[15], g2_n,        1024};
    arr.t[9] = {d_in[16], be2_n,       1024};
    TDescArr td;
    td.t[0] = {d_in[1],  WqkvT,               1024, 1024};
    td.t[1] = {d_in[3],  WqkvT + 1024 * 1024, 1024, 1024};
    td.t[2] = {d_in[5],  WqkvT + 2048 * 1024, 1024, 1024};
    td.t[3] = {d_in[7],  WoT,                 1024, 1024};
    td.t[4] = {d_in[9],  W1T,                 1024, 4096};
    td.t[5] = {d_in[11], W2T,                 4096, 1024};
    preprocess<<<14356, blk, 0, stream>>>(d_in[0], x_n, arr, td);

    // fused QKV projection: M=4096, N=3072, K=1024 -> grid 32x48 = 1536
    gemm_3b<EPI_QKV><<<1536, blk, 73728, stream>>>(
        x_n, 1024, WqkvT, 1024, bqkv, nullptr, Qw, 1024, 1024, 48, Kw, Vw);

    // V transpose for PV B-frags
    vt_transpose<<<dim3(2, 64, 32), blk, 0, stream>>>(Vw, Vt);

    // flash attention (flat grid, XCD-affine bh)
    flash_attn<<<1024, blk, 0, stream>>>(Qw, Kw, Vt, ctx);

    // out-proj + residual, LN1 (grid 32x16 = 512)
    gemm_3b<EPI_RES><<<512, blk, 73728, stream>>>(
        ctx, 1024, WoT, 1024, bo_n, x_n, ln1, 1024, 1024, 16, nullptr, nullptr);
    ln_kernel<<<2048, blk, 0, stream>>>(ln1, g1_n, be1_n, x1, nullptr);

    // FF: gelu(x1@W1+b1)@W2+b2 + x1, LN2 -> d_out
    gemm_3b<EPI_GELU><<<2048, blk, 73728, stream>>>(
        x1, 1024, W1T, 1024, b1_n, nullptr, ff1, 4096, 1024, 64, nullptr, nullptr);
    gemm_3b<EPI_RES><<<512, blk, 73728, stream>>>(
        ff1, 4096, W2T, 4096, b2_n, x1, ff2, 1024, 4096, 16, nullptr, nullptr);
    ln_kernel<<<2048, blk, 0, stream>>>(ff2, g2_n, be2_n, d_out, (const ushort_t*)d_in[0]);
}

// Round 15
// 349.809 us; speedup vs baseline: 1.1258x; 1.1258x over previous
//
#include <hip/hip_runtime.h>
#include <hip/hip_bf16.h>
#include <math.h>

typedef __bf16 bhalf;
typedef __bf16 bhalf8 __attribute__((ext_vector_type(8)));
typedef float  floatx4 __attribute__((ext_vector_type(4)));
typedef float  floatx8 __attribute__((ext_vector_type(8)));
typedef unsigned short ushort_t;
typedef unsigned short ushort8 __attribute__((ext_vector_type(8)));

#define MFMA16(a, b, c) __builtin_amdgcn_mfma_f32_16x16x32_bf16((a), (b), (c), 0, 0, 0)

__device__ __forceinline__ void gload_lds16(const bhalf* g, bhalf* l)
{
    __builtin_amdgcn_global_load_lds((const __attribute__((address_space(1))) void*)g,
                                     (__attribute__((address_space(3))) void*)l, 16, 0, 0);
}

enum { EPI_PLAIN = 0, EPI_RES = 1, EPI_GELU = 2, EPI_QKV = 3 };

// ---------------------------------------------------------------------------
// Dtype detector: flag=1 if inputs are fp32. ONE launch writing a 4-byte
// flag; consumers do a wave-uniform scalar read (broadcast-friendly).
// Round-14 lesson: per-block self-detection (every block re-reading the same
// 4 KB) hotspots the L2 slice holding that line (+26 us total). Keep flag.
// ---------------------------------------------------------------------------
__global__ __launch_bounds__(256) void detect_dtype(const ushort_t* __restrict__ x,
                                                    int* __restrict__ flag)
{
    __shared__ int tot;
    if (threadIdx.x == 0) tot = 0;
    __syncthreads();
    int cnt = 0;
#pragma unroll
    for (int it = 0; it < 8; ++it) {
        const ushort8 u = *(const ushort8*)(x + ((size_t)(it * 256 + threadIdx.x)) * 8);
#pragma unroll
        for (int j = 0; j < 8; j += 2) {
            const int e = (u[j] >> 7) & 0xFF;
            if (e >= 0x90) ++cnt;
        }
    }
    atomicAdd(&tot, cnt);
    __syncthreads();
    if (threadIdx.x == 0) flag[0] = (tot > 64) ? 1 : 0;
}

// ---------------------------------------------------------------------------
// Normalize x (4.19M elems) to bf16; grid exactly 2048 blocks.
// ---------------------------------------------------------------------------
__global__ __launch_bounds__(256) void norm_x(const void* __restrict__ s,
                                              bhalf* __restrict__ d,
                                              const int* __restrict__ flag)
{
    const int i = (blockIdx.x * 256 + threadIdx.x) * 8;
    if (*flag) {
        const floatx8 v = *(const floatx8*)((const float*)s + i);
        bhalf8 o;
#pragma unroll
        for (int j = 0; j < 8; ++j) o[j] = (bhalf)v[j];
        *(bhalf8*)(d + i) = o;
    } else {
        *(ushort8*)((ushort_t*)d + i) = *(const ushort8*)((const ushort_t*)s + i);
    }
}

// ---------------------------------------------------------------------------
// Normalize the 10 small vectors; grid (2, 10).
// ---------------------------------------------------------------------------
struct Cvt { const void* s; bhalf* d; int n; };
struct CvtArr { Cvt t[10]; };

__global__ __launch_bounds__(256) void norm_vec(CvtArr a, const int* __restrict__ flag)
{
    const Cvt c = a.t[blockIdx.y];
    const int i = (blockIdx.x * 256 + threadIdx.x) * 8;
    if (i >= c.n) return;
    if (*flag) {
        const floatx8 v = *(const floatx8*)((const float*)c.s + i);
        bhalf8 o;
#pragma unroll
        for (int j = 0; j < 8; ++j) o[j] = (bhalf)v[j];
        *(bhalf8*)(c.d + i) = o;
    } else {
        *(ushort8*)((ushort_t*)c.d + i) = *(const ushort8*)((const ushort_t*)c.s + i);
    }
}

// ---------------------------------------------------------------------------
// Fused weight transposes: all 6 weights in one launch. in[R][C] -> out[C][R]
// bf16 (+convert per flag). Flat grid of 32x32 tiles; descriptor lookup.
// ---------------------------------------------------------------------------
struct TDesc { const void* src; bhalf* dst; int R, C; };
struct TDescArr { TDesc t[6]; };

__global__ __launch_bounds__(256) void transpose_all(TDescArr a, const int* __restrict__ flag)
{
    __shared__ bhalf sm[32][33];
    const int id = blockIdx.x;
    TDesc d;
    int rem;
    if (id < 4096)      { d = a.t[id >> 10]; rem = id & 1023; }
    else if (id < 8192) { d = a.t[4];        rem = id - 4096; }
    else                { d = a.t[5];        rem = id - 8192; }
    const int txc = d.C >> 5;                 // tiles along C
    const int bx = (rem % txc) * 32;          // col base
    const int by = (rem / txc) * 32;          // row base
    const int tx = threadIdx.x & 31;
    const int ty = threadIdx.x >> 5;
    if (*flag) {
        const float* fin = (const float*)d.src;
#pragma unroll
        for (int i = 0; i < 4; ++i)
            sm[ty + i * 8][tx] = (bhalf)fin[(size_t)(by + ty + i * 8) * d.C + bx + tx];
    } else {
        const bhalf* bin = (const bhalf*)d.src;
#pragma unroll
        for (int i = 0; i < 4; ++i)
            sm[ty + i * 8][tx] = bin[(size_t)(by + ty + i * 8) * d.C + bx + tx];
    }
    __syncthreads();
#pragma unroll
    for (int i = 0; i < 4; ++i)
        d.dst[(size_t)(bx + ty + i * 8) * d.R + by + tx] = sm[tx][ty + i * 8];
}

// ---------------------------------------------------------------------------
// V transpose: Vw[b*2048+t][h*64+dk] -> Vt[(b*16+h)*64+dk][t]. Coalesced.
// ---------------------------------------------------------------------------
__global__ __launch_bounds__(256) void vt_transpose(const bhalf* __restrict__ Vw,
                                                    bhalf* __restrict__ Vt)
{
    __shared__ bhalf sm[32][33];
    const int bh = blockIdx.z;
    const int b = bh >> 4, h = bh & 15;
    const int tb = blockIdx.y * 32;
    const int db = blockIdx.x * 32;
    const int tx = threadIdx.x & 31;
    const int ty = threadIdx.x >> 5;
#pragma unroll
    for (int i = 0; i < 4; ++i)
        sm[ty + i * 8][tx] = Vw[(size_t)(b * 2048 + tb + ty + i * 8) * 1024 + h * 64 + db + tx];
    __syncthreads();
#pragma unroll
    for (int i = 0; i < 4; ++i)
        Vt[(size_t)(bh * 64 + db + ty + i * 8) * 2048 + tb + tx] = sm[tx][ty + i * 8];
}

// ---------------------------------------------------------------------------
// UNIFIED GEMM: 128x64 tile, BK=64, 256 threads (4 waves, wave owns 32x64),
// TRIPLE-buffered LDS (72 KB dynamic -> 2 blocks/CU), prefetch 2 K-tiles
// ahead, counted vmcnt, one barrier per body (round-12/13 verified: 0 bank
// conflicts, FETCH within 5% of ideal after hierarchical mapping).
// Hierarchical tile-id mapping (round 13): XCD chunk traversed in COLUMN
// GROUPS of 16 -> concurrent L2 working set ~3 MB < 4 MB XCD L2.
// Body t: { ds_read 12 frags buf(t%3); stage(t+2)->buf((t+2)%3);
//           16 MFMA (setprio); vmcnt(6) confirms tile t+1; barrier }
// ---------------------------------------------------------------------------
template <int EPI>
__global__ __launch_bounds__(256) void gemm_3b(
    const bhalf* __restrict__ A, int lda,
    const bhalf* __restrict__ BT, int ldb,
    const bhalf* __restrict__ bias,
    const bhalf* __restrict__ resid,
    bhalf* __restrict__ C, int ldc, int K, int nbx,
    bhalf* __restrict__ Ck, bhalf* __restrict__ Cv)
{
    extern __shared__ __align__(16) bhalf sm[];   // A: 3x8192 | B(at 24576): 3x4096

    const int tid  = threadIdx.x;
    const int lane = tid & 63;
    const int w    = tid >> 6;
    const int l15  = lane & 15;
    const int q    = lane >> 4;
    const int wm   = w * 32;

    // XCD chunk + column-grouped traversal (W=16), bijective
    const int nwg = gridDim.x;
    const int cpx = nwg >> 3;
    const int xcd = blockIdx.x & 7;
    const int idc = blockIdx.x >> 3;
    const int rc  = cpx / nbx;
    const int gsz = rc * 16;
    const int g   = idc / gsz;
    const int rm  = idc % gsz;
    const int row = xcd * rc + rm / 16;
    const int col = g * 16 + (rm & 15);
    const int n0  = col * 64;
    const int m0  = row * 128;

    const int r8 = lane >> 3;
    const int c8 = lane & 7;
    const int gc = (c8 ^ r8) << 3;

    floatx4 acc[2][4];
#pragma unroll
    for (int i = 0; i < 2; ++i)
#pragma unroll
        for (int j = 0; j < 4; ++j) acc[i][j] = (floatx4){0.f, 0.f, 0.f, 0.f};

    const bhalf* Ab = A  + (size_t)(m0 + r8) * lda + gc;
    const bhalf* Bb = BT + (size_t)(n0 + r8) * ldb + gc;

    auto stage = [&](int buf, int k0) {
        bhalf* as = sm + buf * 8192;
        bhalf* bs = sm + 24576 + buf * 4096;
#pragma unroll
        for (int i = 0; i < 4; ++i) {
            const int rb = w * 32 + i * 8;
            gload_lds16(Ab + (size_t)rb * lda + k0, as + rb * 64 + lane * 8);
        }
#pragma unroll
        for (int i = 0; i < 2; ++i) {
            const int rb = w * 16 + i * 8;
            gload_lds16(Bb + (size_t)rb * ldb + k0, bs + rb * 64 + lane * 8);
        }
    };

    // prologue: tiles 0,1 issued (12 loads); confirm tile 0 (6 newest in flight)
    stage(0, 0);
    stage(1, 64);
    asm volatile("s_waitcnt vmcnt(6)" ::: "memory");
    __builtin_amdgcn_s_barrier();
    asm volatile("" ::: "memory");

    const int NT = K >> 6;
    for (int t = 0; t < NT; ++t) {
        const int buf = t % 3;
        const bhalf* as = sm + buf * 8192;
        const bhalf* bs = sm + 24576 + buf * 4096;

        bhalf8 af[2][2], bf[2][4];
#pragma unroll
        for (int ks = 0; ks < 2; ++ks) {
            const int pc = (((ks * 4 + q) ^ (l15 & 7)) << 3);
#pragma unroll
            for (int mt = 0; mt < 2; ++mt)
                af[ks][mt] = *(const bhalf8*)&as[(wm + mt * 16 + l15) * 64 + pc];
#pragma unroll
            for (int nt = 0; nt < 4; ++nt)
                bf[ks][nt] = *(const bhalf8*)&bs[(nt * 16 + l15) * 64 + pc];
        }

        if (t + 2 < NT) stage((t + 2) % 3, (t + 2) << 6);

        __builtin_amdgcn_s_setprio(1);
#pragma unroll
        for (int ks = 0; ks < 2; ++ks)
#pragma unroll
            for (int mt = 0; mt < 2; ++mt)
#pragma unroll
                for (int nt = 0; nt < 4; ++nt)
                    acc[mt][nt] = MFMA16(af[ks][mt], bf[ks][nt], acc[mt][nt]);
        __builtin_amdgcn_s_setprio(0);

        if (t + 2 < NT) {
            asm volatile("s_waitcnt vmcnt(6)" ::: "memory");
        } else if (t + 1 < NT) {
            asm volatile("s_waitcnt vmcnt(0)" ::: "memory");
        }
        if (t + 1 < NT) {
            __builtin_amdgcn_s_barrier();
            asm volatile("" ::: "memory");
        }
    }

#pragma unroll
    for (int mt = 0; mt < 2; ++mt)
#pragma unroll
        for (int nt = 0; nt < 4; ++nt) {
            const int col2 = n0 + nt * 16 + l15;
            const float bv = (float)bias[col2];
#pragma unroll
            for (int r = 0; r < 4; ++r) {
                const int row2 = m0 + wm + mt * 16 + q * 4 + r;
                float v = acc[mt][nt][r] + bv;
                if constexpr (EPI == EPI_RES) {
                    v += (float)resid[(size_t)row2 * ldc + col2];
                    C[(size_t)row2 * ldc + col2] = (bhalf)v;
                } else if constexpr (EPI == EPI_GELU) {
                    v = 0.5f * v * (1.f + erff(v * 0.70710678118654752f));
                    C[(size_t)row2 * ldc + col2] = (bhalf)v;
                } else if constexpr (EPI == EPI_QKV) {
                    if (col2 < 1024)       C [(size_t)row2 * 1024 + col2]        = (bhalf)v;
                    else if (col2 < 2048)  Ck[(size_t)row2 * 1024 + col2 - 1024] = (bhalf)v;
                    else                   Cv[(size_t)row2 * 1024 + col2 - 2048] = (bhalf)v;
                } else {
                    C[(size_t)row2 * ldc + col2] = (bhalf)v;
                }
            }
        }
}

// ---------------------------------------------------------------------------
// Flash attention v3: P never touches LDS (swapped QK^T, permuted K rows,
// in-register P pack). Constant-max softmax in exp2 domain. XCD swizzle.
// LDS = 32 KB. (Unchanged.)
// ---------------------------------------------------------------------------
__global__ __launch_bounds__(256) void flash_attn(
    const bhalf* __restrict__ Q, const bhalf* __restrict__ Km,
    const bhalf* __restrict__ Vt, bhalf* __restrict__ ctx)
{
    __shared__ __align__(16) bhalf Ks[2][64 * 64];
    __shared__ __align__(16) bhalf Vs[2][64 * 64];

    const int tid  = threadIdx.x;
    const int lane = tid & 63;
    const int wq   = tid >> 6;
    const int l15  = lane & 15;
    const int q    = lane >> 4;
    const int bh   = blockIdx.x & 31;   // XCD-affine: same head -> same XCD
    const int l0   = (blockIdx.x >> 5) * 64;
    const int b    = bh >> 4, h = bh & 15;
    const float SC = 0.125f * 1.44269504f;

    const bhalf* qp = Q + ((size_t)(b * 2048 + l0 + wq * 16 + l15)) * 1024 + h * 64 + q * 8;
    const bhalf8 aQ0 = *(const bhalf8*)qp;
    const bhalf8 aQ1 = *(const bhalf8*)(qp + 32);

    float ps = 0.f;
    floatx4 o[4];
#pragma unroll
    for (int ot = 0; ot < 4; ++ot) o[ot] = (floatx4){0.f, 0.f, 0.f, 0.f};

    const int r8 = lane >> 3;
    const int c8 = lane & 7;
    const bhalf* kbase = Km + ((size_t)(b * 2048)) * 1024 + h * 64;
    const bhalf* vbase = Vt + ((size_t)(bh * 64)) * 2048;

    auto stage = [&](int buf, int kt) {
#pragma unroll
        for (int i = 0; i < 2; ++i) {
            const int rb = wq * 16 + i * 8;
            const int fk = (((rb >> 3) << 1) ^ r8) & 7;   // K swizzle f(row)
            gload_lds16(kbase + (size_t)(kt + rb + r8) * 1024 + ((c8 ^ fk) << 3),
                        &Ks[buf][rb * 64] + lane * 8);
            gload_lds16(vbase + (size_t)(rb + r8) * 2048 + kt + ((c8 ^ r8) << 3),
                        &Vs[buf][rb * 64] + lane * 8);
        }
    };

    stage(0, 0);
    int cur = 0;
    for (int kt = 0; kt < 2048; kt += 64) {
        __syncthreads();
        if (kt + 64 < 2048) stage(cur ^ 1, kt + 64);

        // ---- S^T = K Q^T (swapped, permuted K rows) ----
        floatx4 s[4];
#pragma unroll
        for (int nt = 0; nt < 4; ++nt) {
            const int row = (nt >> 1) * 32 + (nt & 1) * 4 + ((l15 >> 2) << 3) + (l15 & 3);
            const int f = (((row >> 3) << 1) ^ row) & 7;
            const bhalf8 k0 = *(const bhalf8*)&Ks[cur][row * 64 + ((q ^ f) << 3)];
            const bhalf8 k1 = *(const bhalf8*)&Ks[cur][row * 64 + (((4 + q) ^ f) << 3)];
            floatx4 z = (floatx4){0.f, 0.f, 0.f, 0.f};
            z = MFMA16(k0, aQ0, z);
            s[nt] = MFMA16(k1, aQ1, z);
        }

        // ---- softmax + pack P into PV A-frags (all in registers) ----
        bhalf8 pa[2];
#pragma unroll
        for (int nt = 0; nt < 4; ++nt)
#pragma unroll
            for (int r = 0; r < 4; ++r) {
                const float pv = __builtin_amdgcn_exp2f(fmaf(s[nt][r], SC, -8.f));
                ps += pv;
                pa[nt >> 1][(nt & 1) * 4 + r] = (bhalf)pv;
            }

        // ---- O += P V ----
#pragma unroll
        for (int kc = 0; kc < 2; ++kc)
#pragma unroll
            for (int ot = 0; ot < 4; ++ot) {
                const bhalf8 bV = *(const bhalf8*)&Vs[cur][(ot * 16 + l15) * 64 + (((kc * 4 + q) ^ (l15 & 7)) << 3)];
                o[ot] = MFMA16(pa[kc], bV, o[ot]);
            }
        cur ^= 1;
    }

    // epilogue: denom(query l15) -> redistribute to o rows (query q*4+r)
    ps += __shfl_xor(ps, 16);
    ps += __shfl_xor(ps, 32);
    const float invq = 1.f / ps;
    float inv[4];
#pragma unroll
    for (int r = 0; r < 4; ++r)
        inv[r] = __shfl(invq, (lane & 48) | (q * 4 + r));

#pragma unroll
    for (int ot = 0; ot < 4; ++ot)
#pragma unroll
        for (int r = 0; r < 4; ++r) {
            const int l = l0 + wq * 16 + q * 4 + r;
            const int kk = ot * 16 + l15;
            const int R = h * 128 + (l >> 4);
            const int Cc = (l & 15) * 64 + kk;
            ctx[((size_t)(b * 2048 + R)) * 1024 + Cc] = (bhalf)(o[ot][r] * inv[r]);
        }
}

// ---------------------------------------------------------------------------
// Row LayerNorm, 2 rows/block, bhalf8 vector loads, fp32 stats.
// ---------------------------------------------------------------------------
__global__ __launch_bounds__(256) void ln_kernel(
    const bhalf* __restrict__ X, const bhalf* __restrict__ g,
    const bhalf* __restrict__ be, void* __restrict__ out, const int* __restrict__ flag)
{
    __shared__ float red[4][2];
    const int tid = threadIdx.x;
    const int wid = tid >> 6;
    const int rid = tid >> 7;
    const int lt  = tid & 127;
    const int row = blockIdx.x * 2 + rid;
    const int col = lt * 8;
    const bhalf8 xv = *(const bhalf8*)(X + (size_t)row * 1024 + col);
    float v[8], s1 = 0.f, s2 = 0.f;
#pragma unroll
    for (int i = 0; i < 8; ++i) {
        v[i] = (float)xv[i];
        s1 += v[i];
        s2 += v[i] * v[i];
    }
#pragma unroll
    for (int off = 1; off < 64; off <<= 1) {
        s1 += __shfl_xor(s1, off);
        s2 += __shfl_xor(s2, off);
    }
    if ((tid & 63) == 0) { red[wid][0] = s1; red[wid][1] = s2; }
    __syncthreads();
    const float t1 = red[rid * 2][0] + red[rid * 2 + 1][0];
    const float t2 = red[rid * 2][1] + red[rid * 2 + 1][1];
    const float mu = t1 * (1.f / 1024.f);
    const float rs = rsqrtf(t2 * (1.f / 1024.f) - mu * mu + 1e-5f);
    const bool f32 = flag && (*flag != 0);
    if (f32) {
        floatx8 ov;
#pragma unroll
        for (int i = 0; i < 8; ++i)
            ov[i] = ((v[i] - mu) * rs) * (float)g[col + i] + (float)be[col + i];
        *(floatx8*)((float*)out + (size_t)row * 1024 + col) = ov;
    } else {
        bhalf8 ov;
#pragma unroll
        for (int i = 0; i < 8; ++i)
            ov[i] = (bhalf)(((v[i] - mu) * rs) * (float)g[col + i] + (float)be[col + i]);
        *(bhalf8*)((bhalf*)out + (size_t)row * 1024 + col) = ov;
    }
}

// ---------------------------------------------------------------------------
extern "C" void kernel_launch(void* const* d_in, const int* in_sizes, int n_in,
                              void* d_out, int out_size, void* d_ws, size_t ws_size,
                              hipStream_t stream)
{
    (void)in_sizes; (void)n_in; (void)out_size; (void)ws_size;

    char* p = (char*)d_ws;
    const size_t MB = 1024 * 1024;
    int*   flag  = (int*)p;
    bhalf* vecs  = (bhalf*)(p + 128 * 1024);
    bhalf* Qw    = (bhalf*)(p + 1 * MB);
    bhalf* Kw    = (bhalf*)(p + 9 * MB);
    bhalf* Vw    = (bhalf*)(p + 17 * MB);
    bhalf* Vt    = (bhalf*)(p + 25 * MB);
    bhalf* x_n   = (bhalf*)(p + 33 * MB);
    bhalf* WqkvT = (bhalf*)(p + 41 * MB);
    bhalf* WoT   = (bhalf*)(p + 47 * MB);
    bhalf* W1T   = (bhalf*)(p + 49 * MB);
    bhalf* W2T   = (bhalf*)(p + 57 * MB);
    bhalf* ctx   = Vw;                    // after vt_transpose
    bhalf* ff1   = (bhalf*)(p + 17 * MB); // 32 MB, prior occupants dead
    bhalf* ln1   = Qw;
    bhalf* x1    = Kw;
    bhalf* ff2   = Qw;

    bhalf* bqkv  = vecs;
    bhalf* bo_n  = vecs + 1 * 4096;
    bhalf* b1_n  = vecs + 2 * 4096;
    bhalf* b2_n  = vecs + 3 * 4096;
    bhalf* g1_n  = vecs + 4 * 4096;
    bhalf* be1_n = vecs + 5 * 4096;
    bhalf* g2_n  = vecs + 6 * 4096;
    bhalf* be2_n = vecs + 7 * 4096;

    static bool attr_done = false;
    if (!attr_done) {
        hipFuncSetAttribute((const void*)gemm_3b<EPI_QKV>,
                            hipFuncAttributeMaxDynamicSharedMemorySize, 73728);
        hipFuncSetAttribute((const void*)gemm_3b<EPI_RES>,
                            hipFuncAttributeMaxDynamicSharedMemorySize, 73728);
        hipFuncSetAttribute((const void*)gemm_3b<EPI_GELU>,
                            hipFuncAttributeMaxDynamicSharedMemorySize, 73728);
        attr_done = true;
    }

    const dim3 blk(256);

    detect_dtype<<<1, blk, 0, stream>>>((const ushort_t*)d_in[0], flag);

    norm_x<<<2048, blk, 0, stream>>>(d_in[0], x_n, flag);
    CvtArr arr;
    arr.t[0] = {d_in[2],  bqkv,        1024};
    arr.t[1] = {d_in[4],  bqkv + 1024, 1024};
    arr.t[2] = {d_in[6],  bqkv + 2048, 1024};
    arr.t[3] = {d_in[8],  bo_n,        1024};
    arr.t[4] = {d_in[10], b1_n,        4096};
    arr.t[5] = {d_in[12], b2_n,        1024};
    arr.t[6] = {d_in[13], g1_n,        1024};
    arr.t[7] = {d_in[14], be1_n,       1024};
    arr.t[8] = {d_in[15], g2_n,        1024};
    arr.t[9] = {d_in[16], be2_n,       1024};
    norm_vec<<<dim3(2, 10), blk, 0, stream>>>(arr, flag);

    // all 6 weight transposes in ONE launch
    TDescArr td;
    td.t[0] = {d_in[1],  WqkvT,               1024, 1024};
    td.t[1] = {d_in[3],  WqkvT + 1024 * 1024, 1024, 1024};
    td.t[2] = {d_in[5],  WqkvT + 2048 * 1024, 1024, 1024};
    td.t[3] = {d_in[7],  WoT,                 1024, 1024};
    td.t[4] = {d_in[9],  W1T,                 1024, 4096};
    td.t[5] = {d_in[11], W2T,                 4096, 1024};
    transpose_all<<<12288, blk, 0, stream>>>(td, flag);

    // fused QKV projection: M=4096, N=3072, K=1024 -> grid 32x48 = 1536
    gemm_3b<EPI_QKV><<<1536, blk, 73728, stream>>>(
        x_n, 1024, WqkvT, 1024, bqkv, nullptr, Qw, 1024, 1024, 48, Kw, Vw);

    // V transpose for PV B-frags
    vt_transpose<<<dim3(2, 64, 32), blk, 0, stream>>>(Vw, Vt);

    // flash attention (flat grid, XCD-affine bh)
    flash_attn<<<1024, blk, 0, stream>>>(Qw, Kw, Vt, ctx);

    // out-proj + residual, LN1 (grid 32x16 = 512)
    gemm_3b<EPI_RES><<<512, blk, 73728, stream>>>(
        ctx, 1024, WoT, 1024, bo_n, x_n, ln1, 1024, 1024, 16, nullptr, nullptr);
    ln_kernel<<<2048, blk, 0, stream>>>(ln1, g1_n, be1_n, x1, nullptr);

    // FF: gelu(x1@W1+b1)@W2+b2 + x1, LN2 -> d_out
    gemm_3b<EPI_GELU><<<2048, blk, 73728, stream>>>(
        x1, 1024, W1T, 1024, b1_n, nullptr, ff1, 4096, 1024, 64, nullptr, nullptr);
    gemm_3b<EPI_RES><<<512, blk, 73728, stream>>>(
        ff1, 4096, W2T, 4096, b2_n, x1, ff2, 1024, 4096, 16, nullptr, nullptr);
    ln_kernel<<<2048, blk, 0, stream>>>(ff2, g2_n, be2_n, d_out, flag);
}